// Round 1
// baseline (1045.345 us; speedup 1.0000x reference)
//
#include <hip/hip_runtime.h>

#define Bb 4
#define Ss 2048
#define Hh 1024
#define Mm (Bb * Ss)   // 8192 rows

__device__ __forceinline__ float sigf(float z) { return 1.0f / (1.0f + __expf(-z)); }

// ---------------------------------------------------------------------------
// Fused projection GEMM: for row-block of x [M,K], compute
//   z_i = x@Wi^T, z_f = x@Wf^T, z_g = x@Wg^T   (W row-major [N,K], K contiguous)
// epilogue: f = sigmoid(z_f); inp = z_i*sigmoid(z_i)*(1-f); g = z_g
// 64x64 tile, BK=16, 256 threads, 4x4 micro-tile per thread.
// ---------------------------------------------------------------------------
__global__ __launch_bounds__(256) void proj_kernel(
    const float* __restrict__ x,  const float* __restrict__ Wi,
    const float* __restrict__ Wf, const float* __restrict__ Wg,
    float* __restrict__ f_out, float* __restrict__ inp_out, float* __restrict__ g_out)
{
    // +4 pad keeps rows 16B-aligned (68 floats = 17*16B) and breaks pow2 strides
    __shared__ __align__(16) float As [16][68];
    __shared__ __align__(16) float Bis[16][68];
    __shared__ __align__(16) float Bfs[16][68];
    __shared__ __align__(16) float Bgs[16][68];

    const int tid = threadIdx.x;
    const int tx  = tid & 15;   // n-direction (4 cols each)
    const int ty  = tid >> 4;   // m-direction (4 rows each)
    const int m0  = blockIdx.x * 64;
    const int n0  = blockIdx.y * 64;
    const int lr  = tid >> 2;        // tile row 0..63 for staging loads
    const int lk  = (tid & 3) << 2;  // k offset 0,4,8,12

    float acc_i[4][4] = {}, acc_f[4][4] = {}, acc_g[4][4] = {};

    const float* pA = x  + (size_t)(m0 + lr) * Hh + lk;
    const float* pI = Wi + (size_t)(n0 + lr) * Hh + lk;
    const float* pF = Wf + (size_t)(n0 + lr) * Hh + lk;
    const float* pG = Wg + (size_t)(n0 + lr) * Hh + lk;

    for (int k0 = 0; k0 < Hh; k0 += 16) {
        const float4 av = *(const float4*)(pA + k0);
        const float4 iv = *(const float4*)(pI + k0);
        const float4 fv = *(const float4*)(pF + k0);
        const float4 gv = *(const float4*)(pG + k0);
        __syncthreads();  // previous iteration's readers done
        As [lk+0][lr] = av.x; As [lk+1][lr] = av.y; As [lk+2][lr] = av.z; As [lk+3][lr] = av.w;
        Bis[lk+0][lr] = iv.x; Bis[lk+1][lr] = iv.y; Bis[lk+2][lr] = iv.z; Bis[lk+3][lr] = iv.w;
        Bfs[lk+0][lr] = fv.x; Bfs[lk+1][lr] = fv.y; Bfs[lk+2][lr] = fv.z; Bfs[lk+3][lr] = fv.w;
        Bgs[lk+0][lr] = gv.x; Bgs[lk+1][lr] = gv.y; Bgs[lk+2][lr] = gv.z; Bgs[lk+3][lr] = gv.w;
        __syncthreads();
        #pragma unroll
        for (int kk = 0; kk < 16; ++kk) {
            const float4 a  = *(const float4*)&As [kk][ty << 2];
            const float4 bi = *(const float4*)&Bis[kk][tx << 2];
            const float4 bf = *(const float4*)&Bfs[kk][tx << 2];
            const float4 bg = *(const float4*)&Bgs[kk][tx << 2];
            const float aa[4]  = {a.x,  a.y,  a.z,  a.w};
            const float bbi[4] = {bi.x, bi.y, bi.z, bi.w};
            const float bbf[4] = {bf.x, bf.y, bf.z, bf.w};
            const float bbg[4] = {bg.x, bg.y, bg.z, bg.w};
            #pragma unroll
            for (int i = 0; i < 4; ++i)
                #pragma unroll
                for (int j = 0; j < 4; ++j) {
                    acc_i[i][j] = fmaf(aa[i], bbi[j], acc_i[i][j]);
                    acc_f[i][j] = fmaf(aa[i], bbf[j], acc_f[i][j]);
                    acc_g[i][j] = fmaf(aa[i], bbg[j], acc_g[i][j]);
                }
        }
    }

    #pragma unroll
    for (int i = 0; i < 4; ++i) {
        const size_t row = (size_t)(m0 + (ty << 2) + i) * Hh + n0 + (tx << 2);
        float4 vf, vp, vg;
        float* qf = (float*)&vf; float* qp = (float*)&vp; float* qg = (float*)&vg;
        #pragma unroll
        for (int j = 0; j < 4; ++j) {
            const float f  = sigf(acc_f[i][j]);
            const float zi = acc_i[i][j];
            qf[j] = f;
            qp[j] = zi * sigf(zi) * (1.0f - f);
            qg[j] = acc_g[i][j];
        }
        *(float4*)(f_out   + row) = vf;
        *(float4*)(inp_out + row) = vp;
        *(float4*)(g_out   + row) = vg;
    }
}

// ---------------------------------------------------------------------------
// Linear recurrence: h_t = f_t*h_{t-1} + inp_t ; gh_t = g_t*h_t
// One thread per (b,h) chain; gh written in-place over f (same-thread RAW ok,
// hence NO __restrict__ on f/gh). Chunked x8 loads for latency pipelining.
// ---------------------------------------------------------------------------
__global__ __launch_bounds__(256) void recur_kernel(
    const float* f_buf, const float* __restrict__ inp_buf,
    const float* __restrict__ g_buf, float* gh_out)
{
    const int t = blockIdx.x * 256 + threadIdx.x;   // 0..4095
    const int b = t >> 10;
    const int h = t & 1023;
    const size_t base = (size_t)b * Ss * Hh + h;
    float hh = 0.0f;
    for (int s0 = 0; s0 < Ss; s0 += 8) {
        float fr[8], ir[8], gr[8], o[8];
        #pragma unroll
        for (int j = 0; j < 8; ++j) {
            const size_t off = base + (size_t)(s0 + j) * Hh;
            fr[j] = f_buf[off]; ir[j] = inp_buf[off]; gr[j] = g_buf[off];
        }
        #pragma unroll
        for (int j = 0; j < 8; ++j) {
            hh = fmaf(fr[j], hh, ir[j]);
            o[j] = gr[j] * hh;
        }
        #pragma unroll
        for (int j = 0; j < 8; ++j)
            gh_out[base + (size_t)(s0 + j) * Hh] = o[j];
    }
}

// ---------------------------------------------------------------------------
// Output GEMM: out = gh @ Wo^T  (same tile structure as proj, single B matrix)
// ---------------------------------------------------------------------------
__global__ __launch_bounds__(256) void out_kernel(
    const float* __restrict__ A, const float* __restrict__ Wo,
    float* __restrict__ out)
{
    __shared__ __align__(16) float As[16][68];
    __shared__ __align__(16) float Bs[16][68];

    const int tid = threadIdx.x;
    const int tx  = tid & 15;
    const int ty  = tid >> 4;
    const int m0  = blockIdx.x * 64;
    const int n0  = blockIdx.y * 64;
    const int lr  = tid >> 2;
    const int lk  = (tid & 3) << 2;

    float acc[4][4] = {};

    const float* pA = A  + (size_t)(m0 + lr) * Hh + lk;
    const float* pB = Wo + (size_t)(n0 + lr) * Hh + lk;

    for (int k0 = 0; k0 < Hh; k0 += 16) {
        const float4 av = *(const float4*)(pA + k0);
        const float4 bv = *(const float4*)(pB + k0);
        __syncthreads();
        As[lk+0][lr] = av.x; As[lk+1][lr] = av.y; As[lk+2][lr] = av.z; As[lk+3][lr] = av.w;
        Bs[lk+0][lr] = bv.x; Bs[lk+1][lr] = bv.y; Bs[lk+2][lr] = bv.z; Bs[lk+3][lr] = bv.w;
        __syncthreads();
        #pragma unroll
        for (int kk = 0; kk < 16; ++kk) {
            const float4 a = *(const float4*)&As[kk][ty << 2];
            const float4 b = *(const float4*)&Bs[kk][tx << 2];
            const float aa[4] = {a.x, a.y, a.z, a.w};
            const float bb[4] = {b.x, b.y, b.z, b.w};
            #pragma unroll
            for (int i = 0; i < 4; ++i)
                #pragma unroll
                for (int j = 0; j < 4; ++j)
                    acc[i][j] = fmaf(aa[i], bb[j], acc[i][j]);
        }
    }

    #pragma unroll
    for (int i = 0; i < 4; ++i) {
        const size_t row = (size_t)(m0 + (ty << 2) + i) * Hh + n0 + (tx << 2);
        float4 v;
        ((float*)&v)[0] = acc[i][0]; ((float*)&v)[1] = acc[i][1];
        ((float*)&v)[2] = acc[i][2]; ((float*)&v)[3] = acc[i][3];
        *(float4*)(out + row) = v;
    }
}

extern "C" void kernel_launch(void* const* d_in, const int* in_sizes, int n_in,
                              void* d_out, int out_size, void* d_ws, size_t ws_size,
                              hipStream_t stream) {
    const float* x  = (const float*)d_in[0];
    const float* Wi = (const float*)d_in[1];
    const float* Wf = (const float*)d_in[2];
    const float* Wg = (const float*)d_in[3];
    const float* Wo = (const float*)d_in[4];
    float* out = (float*)d_out;

    // ws layout: f_buf [M*H], inp_buf [M*H]  (needs 64 MiB). g goes to d_out
    // (scratch until the final GEMM overwrites it). gh overwrites f_buf.
    float* f_buf   = (float*)d_ws;
    float* inp_buf = f_buf + (size_t)Mm * Hh;

    dim3 grid(Mm / 64, Hh / 64);  // 128 x 16
    proj_kernel<<<grid, 256, 0, stream>>>(x, Wi, Wf, Wg, f_buf, inp_buf, out);
    recur_kernel<<<16, 256, 0, stream>>>(f_buf, inp_buf, out, f_buf);
    out_kernel<<<grid, 256, 0, stream>>>(f_buf, Wo, out);
}

// Round 2
// 833.331 us; speedup vs baseline: 1.2544x; 1.2544x over previous
//
#include <hip/hip_runtime.h>

#define Bb 4
#define Ss 2048
#define Hh 1024
#define Mm (Bb * Ss)   // 8192 rows
#define NC 32          // recurrence chunks
#define CL 64          // chunk length (NC*CL == Ss)

typedef short  s16x8 __attribute__((ext_vector_type(8)));
typedef float  f32x4 __attribute__((ext_vector_type(4)));

__device__ __forceinline__ float sigf(float z) { return 1.0f / (1.0f + __expf(-z)); }

// bf16 round-to-nearest-even helpers (bit-level, no API dependence)
__device__ __forceinline__ unsigned short f2bf(float x) {
    unsigned int u = __float_as_uint(x);
    u += 0x7FFFu + ((u >> 16) & 1u);
    return (unsigned short)(u >> 16);
}
__device__ __forceinline__ float bf2f(unsigned short h) {
    return __uint_as_float(((unsigned int)h) << 16);
}

// ---------------------------------------------------------------------------
// Split fp32 -> (bf16 hi, bf16 lo), 4 elems/thread, vectorized
// ---------------------------------------------------------------------------
__global__ __launch_bounds__(256) void conv_split(
    const float* __restrict__ src, unsigned short* __restrict__ dh,
    unsigned short* __restrict__ dl, int n4)
{
    const int i = blockIdx.x * 256 + threadIdx.x;
    if (i >= n4) return;
    const float4 v = ((const float4*)src)[i];
    ushort4 h4, l4;
    const float vv[4] = {v.x, v.y, v.z, v.w};
    unsigned short* hp = (unsigned short*)&h4;
    unsigned short* lp = (unsigned short*)&l4;
    #pragma unroll
    for (int j = 0; j < 4; ++j) {
        const unsigned short hi = f2bf(vv[j]);
        hp[j] = hi;
        lp[j] = f2bf(vv[j] - bf2f(hi));
    }
    ((ushort4*)dh)[i] = h4;
    ((ushort4*)dl)[i] = l4;
}

// ---------------------------------------------------------------------------
// Split-bf16 MFMA GEMM: C[M=8192, N=1024] = A[M,K=1024] @ B[N,K]^T
// A,B given as hi/lo bf16 pairs; acc = Ah*Bh + Al*Bh + Ah*Bl (fp32 MFMA acc).
// 128x128 tile, 256 threads (4 waves, each 64x64 = 4x4 tiles of 16x16x32).
// MODE 0: store raw   MODE 1: store sigmoid(z)   MODE 2: store silu(z)*(1-Faux)
// ---------------------------------------------------------------------------
template<int MODE>
__global__ __launch_bounds__(256, 2) void gemm_split(
    const unsigned short* __restrict__ Ah, const unsigned short* __restrict__ Al,
    const unsigned short* __restrict__ Bh, const unsigned short* __restrict__ Bl,
    const float* __restrict__ Faux, float* __restrict__ C)
{
    // padded stride 40 shorts (80 B): 16B-aligned rows, balanced banks
    __shared__ __align__(16) unsigned short As_h[128 * 40];
    __shared__ __align__(16) unsigned short As_l[128 * 40];
    __shared__ __align__(16) unsigned short Bs_h[128 * 40];
    __shared__ __align__(16) unsigned short Bs_l[128 * 40];

    const int tid  = threadIdx.x;
    const int lane = tid & 63;
    const int wave = tid >> 6;
    const int wm   = (wave & 1) * 64;   // wave m-origin in tile
    const int wn   = (wave >> 1) * 64;  // wave n-origin in tile
    const int lm   = lane & 15;
    const int kq   = lane >> 4;         // k-quad 0..3
    const int m0   = blockIdx.y * 128;
    const int n0   = blockIdx.x * 128;

    f32x4 acc[4][4] = {};

    // staging: 2 chunks/thread, each 16B = 8 bf16
    const int row0 = tid >> 2;            // chunk it=0: rows 0..63
    const int kc   = (tid & 3) << 3;      // k offset 0,8,16,24

    for (int k0 = 0; k0 < Hh; k0 += 32) {
        uint4 va_h[2], va_l[2], vb_h[2], vb_l[2];
        #pragma unroll
        for (int it = 0; it < 2; ++it) {
            const int row = row0 + 64 * it;
            const size_t ga = (size_t)(m0 + row) * Hh + k0 + kc;
            const size_t gb = (size_t)(n0 + row) * Hh + k0 + kc;
            va_h[it] = *(const uint4*)(Ah + ga);
            va_l[it] = *(const uint4*)(Al + ga);
            vb_h[it] = *(const uint4*)(Bh + gb);
            vb_l[it] = *(const uint4*)(Bl + gb);
        }
        __syncthreads();  // previous iteration's LDS readers done
        #pragma unroll
        for (int it = 0; it < 2; ++it) {
            const int row = row0 + 64 * it;
            const int li  = row * 40 + kc;
            *(uint4*)&As_h[li] = va_h[it];
            *(uint4*)&As_l[li] = va_l[it];
            *(uint4*)&Bs_h[li] = vb_h[it];
            *(uint4*)&Bs_l[li] = vb_l[it];
        }
        __syncthreads();

        s16x8 ah[4], al[4], bh[4], bl[4];
        #pragma unroll
        for (int t = 0; t < 4; ++t) {
            const int ia = (wm + t * 16 + lm) * 40 + kq * 8;
            const int ib = (wn + t * 16 + lm) * 40 + kq * 8;
            ah[t] = *(const s16x8*)&As_h[ia];
            al[t] = *(const s16x8*)&As_l[ia];
            bh[t] = *(const s16x8*)&Bs_h[ib];
            bl[t] = *(const s16x8*)&Bs_l[ib];
        }
        #pragma unroll
        for (int mi = 0; mi < 4; ++mi)
            #pragma unroll
            for (int ni = 0; ni < 4; ++ni) {
                acc[mi][ni] = __builtin_amdgcn_mfma_f32_16x16x32_bf16(ah[mi], bh[ni], acc[mi][ni], 0, 0, 0);
                acc[mi][ni] = __builtin_amdgcn_mfma_f32_16x16x32_bf16(al[mi], bh[ni], acc[mi][ni], 0, 0, 0);
                acc[mi][ni] = __builtin_amdgcn_mfma_f32_16x16x32_bf16(ah[mi], bl[ni], acc[mi][ni], 0, 0, 0);
            }
    }

    // epilogue: D[row = kq*4 + r][col = lm] per 16x16 tile
    #pragma unroll
    for (int mi = 0; mi < 4; ++mi)
        #pragma unroll
        for (int ni = 0; ni < 4; ++ni) {
            const int n = n0 + wn + ni * 16 + lm;
            #pragma unroll
            for (int r = 0; r < 4; ++r) {
                const int m = m0 + wm + mi * 16 + kq * 4 + r;
                const size_t idx = (size_t)m * Hh + n;
                const float z = acc[mi][ni][r];
                float v;
                if (MODE == 0)      v = z;
                else if (MODE == 1) v = sigf(z);
                else                v = z * sigf(z) * (1.0f - Faux[idx]);
                C[idx] = v;
            }
        }
}

// ---------------------------------------------------------------------------
// Recurrence pass 1: per (b,h,chunk) compute P = prod(f), L = local final h
// ---------------------------------------------------------------------------
__global__ __launch_bounds__(256) void scan1(
    const float* __restrict__ f, const float* __restrict__ ip,
    float2* __restrict__ csum)
{
    const int g  = blockIdx.x * 256 + threadIdx.x;  // 0..131071
    const int c  = g >> 12;                          // chunk 0..31
    const int bh = g & 4095;
    const size_t base = (size_t)(bh >> 10) * ((size_t)Ss * Hh) + (bh & 1023);
    const int s0 = c * CL;
    float P = 1.0f, L = 0.0f;
    for (int j = 0; j < CL; j += 4) {
        float fv[4], iv[4];
        #pragma unroll
        for (int q = 0; q < 4; ++q) {
            const size_t off = base + (size_t)(s0 + j + q) * Hh;
            fv[q] = f[off]; iv[q] = ip[off];
        }
        #pragma unroll
        for (int q = 0; q < 4; ++q) { L = fmaf(fv[q], L, iv[q]); P *= fv[q]; }
    }
    csum[(size_t)bh * NC + c] = make_float2(P, L);
}

// ---------------------------------------------------------------------------
// Recurrence pass 2: combine chunk prefixes, replay chunk, emit gh as bf16 hi/lo
// ---------------------------------------------------------------------------
__global__ __launch_bounds__(256) void scan2(
    const float* __restrict__ f, const float* __restrict__ ip,
    const float* __restrict__ gbuf, const float2* __restrict__ csum,
    unsigned short* __restrict__ ghh, unsigned short* __restrict__ ghl)
{
    const int g  = blockIdx.x * 256 + threadIdx.x;
    const int c  = g >> 12;
    const int bh = g & 4095;
    const size_t base = (size_t)(bh >> 10) * ((size_t)Ss * Hh) + (bh & 1023);
    float h = 0.0f;
    for (int cp = 0; cp < c; ++cp) {
        const float2 pl = csum[(size_t)bh * NC + cp];
        h = fmaf(pl.x, h, pl.y);
    }
    const int s0 = c * CL;
    for (int j = 0; j < CL; j += 4) {
        float fv[4], iv[4], gv[4];
        #pragma unroll
        for (int q = 0; q < 4; ++q) {
            const size_t off = base + (size_t)(s0 + j + q) * Hh;
            fv[q] = f[off]; iv[q] = ip[off]; gv[q] = gbuf[off];
        }
        #pragma unroll
        for (int q = 0; q < 4; ++q) {
            h = fmaf(fv[q], h, iv[q]);
            const float gh = gv[q] * h;
            const unsigned short hi = f2bf(gh);
            const size_t off = base + (size_t)(s0 + j + q) * Hh;
            ghh[off] = hi;
            ghl[off] = f2bf(gh - bf2f(hi));
        }
    }
}

// ===========================================================================
// Round-1 fp32 fallback (used only if ws_size is too small for the split path)
// ===========================================================================
__global__ __launch_bounds__(256) void proj_kernel(
    const float* __restrict__ x,  const float* __restrict__ Wi,
    const float* __restrict__ Wf, const float* __restrict__ Wg,
    float* __restrict__ f_out, float* __restrict__ inp_out, float* __restrict__ g_out)
{
    __shared__ __align__(16) float As [16][68];
    __shared__ __align__(16) float Bis[16][68];
    __shared__ __align__(16) float Bfs[16][68];
    __shared__ __align__(16) float Bgs[16][68];
    const int tid = threadIdx.x;
    const int tx = tid & 15, ty = tid >> 4;
    const int m0 = blockIdx.x * 64, n0 = blockIdx.y * 64;
    const int lr = tid >> 2, lk = (tid & 3) << 2;
    float acc_i[4][4] = {}, acc_f[4][4] = {}, acc_g[4][4] = {};
    const float* pA = x  + (size_t)(m0 + lr) * Hh + lk;
    const float* pI = Wi + (size_t)(n0 + lr) * Hh + lk;
    const float* pF = Wf + (size_t)(n0 + lr) * Hh + lk;
    const float* pG = Wg + (size_t)(n0 + lr) * Hh + lk;
    for (int k0 = 0; k0 < Hh; k0 += 16) {
        const float4 av = *(const float4*)(pA + k0);
        const float4 iv = *(const float4*)(pI + k0);
        const float4 fv = *(const float4*)(pF + k0);
        const float4 gv = *(const float4*)(pG + k0);
        __syncthreads();
        As [lk+0][lr] = av.x; As [lk+1][lr] = av.y; As [lk+2][lr] = av.z; As [lk+3][lr] = av.w;
        Bis[lk+0][lr] = iv.x; Bis[lk+1][lr] = iv.y; Bis[lk+2][lr] = iv.z; Bis[lk+3][lr] = iv.w;
        Bfs[lk+0][lr] = fv.x; Bfs[lk+1][lr] = fv.y; Bfs[lk+2][lr] = fv.z; Bfs[lk+3][lr] = fv.w;
        Bgs[lk+0][lr] = gv.x; Bgs[lk+1][lr] = gv.y; Bgs[lk+2][lr] = gv.z; Bgs[lk+3][lr] = gv.w;
        __syncthreads();
        #pragma unroll
        for (int kk = 0; kk < 16; ++kk) {
            const float4 a  = *(const float4*)&As [kk][ty << 2];
            const float4 bi = *(const float4*)&Bis[kk][tx << 2];
            const float4 bf = *(const float4*)&Bfs[kk][tx << 2];
            const float4 bg = *(const float4*)&Bgs[kk][tx << 2];
            const float aa[4]  = {a.x,a.y,a.z,a.w};
            const float bbi[4] = {bi.x,bi.y,bi.z,bi.w};
            const float bbf[4] = {bf.x,bf.y,bf.z,bf.w};
            const float bbg[4] = {bg.x,bg.y,bg.z,bg.w};
            #pragma unroll
            for (int i = 0; i < 4; ++i)
                #pragma unroll
                for (int j = 0; j < 4; ++j) {
                    acc_i[i][j] = fmaf(aa[i], bbi[j], acc_i[i][j]);
                    acc_f[i][j] = fmaf(aa[i], bbf[j], acc_f[i][j]);
                    acc_g[i][j] = fmaf(aa[i], bbg[j], acc_g[i][j]);
                }
        }
    }
    #pragma unroll
    for (int i = 0; i < 4; ++i) {
        const size_t row = (size_t)(m0 + (ty << 2) + i) * Hh + n0 + (tx << 2);
        float4 vf, vp, vg;
        float* qf = (float*)&vf; float* qp = (float*)&vp; float* qg = (float*)&vg;
        #pragma unroll
        for (int j = 0; j < 4; ++j) {
            const float ff = sigf(acc_f[i][j]);
            const float zi = acc_i[i][j];
            qf[j] = ff; qp[j] = zi * sigf(zi) * (1.0f - ff); qg[j] = acc_g[i][j];
        }
        *(float4*)(f_out + row) = vf;
        *(float4*)(inp_out + row) = vp;
        *(float4*)(g_out + row) = vg;
    }
}

__global__ __launch_bounds__(256) void recur_kernel(
    const float* f_buf, const float* __restrict__ inp_buf,
    const float* __restrict__ g_buf, float* gh_out)
{
    const int t = blockIdx.x * 256 + threadIdx.x;
    const int b = t >> 10, h = t & 1023;
    const size_t base = (size_t)b * Ss * Hh + h;
    float hh = 0.0f;
    for (int s0 = 0; s0 < Ss; s0 += 8) {
        float fr[8], ir[8], gr[8], o[8];
        #pragma unroll
        for (int j = 0; j < 8; ++j) {
            const size_t off = base + (size_t)(s0 + j) * Hh;
            fr[j] = f_buf[off]; ir[j] = inp_buf[off]; gr[j] = g_buf[off];
        }
        #pragma unroll
        for (int j = 0; j < 8; ++j) { hh = fmaf(fr[j], hh, ir[j]); o[j] = gr[j] * hh; }
        #pragma unroll
        for (int j = 0; j < 8; ++j) gh_out[base + (size_t)(s0 + j) * Hh] = o[j];
    }
}

__global__ __launch_bounds__(256) void out_kernel(
    const float* __restrict__ A, const float* __restrict__ Wo, float* __restrict__ out)
{
    __shared__ __align__(16) float As[16][68];
    __shared__ __align__(16) float Bs[16][68];
    const int tid = threadIdx.x;
    const int tx = tid & 15, ty = tid >> 4;
    const int m0 = blockIdx.x * 64, n0 = blockIdx.y * 64;
    const int lr = tid >> 2, lk = (tid & 3) << 2;
    float acc[4][4] = {};
    const float* pA = A  + (size_t)(m0 + lr) * Hh + lk;
    const float* pB = Wo + (size_t)(n0 + lr) * Hh + lk;
    for (int k0 = 0; k0 < Hh; k0 += 16) {
        const float4 av = *(const float4*)(pA + k0);
        const float4 bv = *(const float4*)(pB + k0);
        __syncthreads();
        As[lk+0][lr] = av.x; As[lk+1][lr] = av.y; As[lk+2][lr] = av.z; As[lk+3][lr] = av.w;
        Bs[lk+0][lr] = bv.x; Bs[lk+1][lr] = bv.y; Bs[lk+2][lr] = bv.z; Bs[lk+3][lr] = bv.w;
        __syncthreads();
        #pragma unroll
        for (int kk = 0; kk < 16; ++kk) {
            const float4 a = *(const float4*)&As[kk][ty << 2];
            const float4 b = *(const float4*)&Bs[kk][tx << 2];
            const float aa[4] = {a.x,a.y,a.z,a.w};
            const float bb[4] = {b.x,b.y,b.z,b.w};
            #pragma unroll
            for (int i = 0; i < 4; ++i)
                #pragma unroll
                for (int j = 0; j < 4; ++j)
                    acc[i][j] = fmaf(aa[i], bb[j], acc[i][j]);
        }
    }
    #pragma unroll
    for (int i = 0; i < 4; ++i) {
        const size_t row = (size_t)(m0 + (ty << 2) + i) * Hh + n0 + (tx << 2);
        float4 v;
        ((float*)&v)[0]=acc[i][0]; ((float*)&v)[1]=acc[i][1];
        ((float*)&v)[2]=acc[i][2]; ((float*)&v)[3]=acc[i][3];
        *(float4*)(out + row) = v;
    }
}

extern "C" void kernel_launch(void* const* d_in, const int* in_sizes, int n_in,
                              void* d_out, int out_size, void* d_ws, size_t ws_size,
                              hipStream_t stream) {
    const float* x  = (const float*)d_in[0];
    const float* Wi = (const float*)d_in[1];
    const float* Wf = (const float*)d_in[2];
    const float* Wg = (const float*)d_in[3];
    const float* Wo = (const float*)d_in[4];
    float* out = (float*)d_out;

    const size_t MH = (size_t)Mm * Hh;      // 8388608
    const size_t HH = (size_t)Hh * Hh;      // 1048576

    // ws layout (split path):
    // xh[MH]u16, xl[MH]u16, Wh[4*HH]u16, Wl[4*HH]u16,
    // f_buf[MH]f32, inp_buf[MH]f32, ghh[MH]u16, ghl[MH]u16, csum[4096*NC]float2
    size_t need = MH*2*2 + HH*4*2*2 + MH*4*2 + MH*2*2 + (size_t)4096*NC*8;

    if (ws_size >= need) {
        char* p = (char*)d_ws;
        unsigned short* xh = (unsigned short*)p;            p += MH*2;
        unsigned short* xl = (unsigned short*)p;            p += MH*2;
        unsigned short* Wh = (unsigned short*)p;            p += HH*4*2;
        unsigned short* Wl = (unsigned short*)p;            p += HH*4*2;
        float* f_buf   = (float*)p;                         p += MH*4;
        float* inp_buf = (float*)p;                         p += MH*4;
        unsigned short* ghh = (unsigned short*)p;           p += MH*2;
        unsigned short* ghl = (unsigned short*)p;           p += MH*2;
        float2* csum = (float2*)p;

        unsigned short* Wih = Wh;          unsigned short* Wil = Wl;
        unsigned short* Wfh = Wh + HH;     unsigned short* Wfl = Wl + HH;
        unsigned short* Wgh = Wh + 2*HH;   unsigned short* Wgl = Wl + 2*HH;
        unsigned short* Woh = Wh + 3*HH;   unsigned short* Wol = Wl + 3*HH;

        // 1. split conversions
        conv_split<<<(int)(MH/4/256), 256, 0, stream>>>(x,  xh,  xl,  (int)(MH/4));
        conv_split<<<(int)(HH/4/256), 256, 0, stream>>>(Wi, Wih, Wil, (int)(HH/4));
        conv_split<<<(int)(HH/4/256), 256, 0, stream>>>(Wf, Wfh, Wfl, (int)(HH/4));
        conv_split<<<(int)(HH/4/256), 256, 0, stream>>>(Wg, Wgh, Wgl, (int)(HH/4));
        conv_split<<<(int)(HH/4/256), 256, 0, stream>>>(Wo, Woh, Wol, (int)(HH/4));

        dim3 gg(Hh/128, Mm/128);  // (8, 64)
        // 2. f = sigmoid(x@Wf^T)
        gemm_split<1><<<gg, 256, 0, stream>>>(xh, xl, Wfh, Wfl, nullptr, f_buf);
        // 3. inp = silu(x@Wi^T) * (1-f)
        gemm_split<2><<<gg, 256, 0, stream>>>(xh, xl, Wih, Wil, f_buf, inp_buf);
        // 4. g = x@Wg^T  (stored in d_out as scratch)
        gemm_split<0><<<gg, 256, 0, stream>>>(xh, xl, Wgh, Wgl, nullptr, out);
        // 5-6. chunked linear recurrence, emits gh as bf16 hi/lo
        scan1<<<512, 256, 0, stream>>>(f_buf, inp_buf, csum);
        scan2<<<512, 256, 0, stream>>>(f_buf, inp_buf, out, csum, ghh, ghl);
        // 7. out = gh @ Wo^T
        gemm_split<0><<<gg, 256, 0, stream>>>(ghh, ghl, Woh, Wol, nullptr, out);
    } else {
        // fp32 fallback (round-1 path)
        float* f_buf   = (float*)d_ws;
        float* inp_buf = f_buf + MH;
        dim3 grid(Mm / 64, Hh / 64);
        proj_kernel<<<grid, 256, 0, stream>>>(x, Wi, Wf, Wg, f_buf, inp_buf, out);
        recur_kernel<<<16, 256, 0, stream>>>(f_buf, inp_buf, out, f_buf);
        out_kernel<<<grid, 256, 0, stream>>>(f_buf, Wo, out);
    }
}

// Round 3
// 415.471 us; speedup vs baseline: 2.5160x; 2.0057x over previous
//
#include <hip/hip_runtime.h>

#define Bb 4
#define Ss 2048
#define Hh 1024
#define Mm (Bb * Ss)   // 8192 rows
#define NC 32          // recurrence chunks
#define CL 64          // chunk length (NC*CL == Ss)

typedef short  s16x8 __attribute__((ext_vector_type(8)));
typedef float  f32x4 __attribute__((ext_vector_type(4)));

__device__ __forceinline__ float sigf(float z) { return 1.0f / (1.0f + __expf(-z)); }

// bf16 round-to-nearest-even helpers (bit-level, no API dependence)
__device__ __forceinline__ unsigned short f2bf(float x) {
    unsigned int u = __float_as_uint(x);
    u += 0x7FFFu + ((u >> 16) & 1u);
    return (unsigned short)(u >> 16);
}
__device__ __forceinline__ float bf2f(unsigned short h) {
    return __uint_as_float(((unsigned int)h) << 16);
}

// async global->LDS, 16B per lane. LDS dst = wave-uniform base + lane*16;
// we pass lane0-consistent per-lane pointers so both semantics coincide.
__device__ __forceinline__ void gl2lds16(const unsigned short* g, unsigned short* l) {
    __builtin_amdgcn_global_load_lds(
        (const __attribute__((address_space(1))) void*)g,
        (__attribute__((address_space(3))) void*)l,
        16, 0, 0);
}

// ---------------------------------------------------------------------------
// Split fp32 -> (bf16 hi, bf16 lo), 4 elems/thread, vectorized
// ---------------------------------------------------------------------------
__global__ __launch_bounds__(256) void conv_split(
    const float* __restrict__ src, unsigned short* __restrict__ dh,
    unsigned short* __restrict__ dl, int n4)
{
    const int i = blockIdx.x * 256 + threadIdx.x;
    if (i >= n4) return;
    const float4 v = ((const float4*)src)[i];
    ushort4 h4, l4;
    const float vv[4] = {v.x, v.y, v.z, v.w};
    unsigned short* hp = (unsigned short*)&h4;
    unsigned short* lp = (unsigned short*)&l4;
    #pragma unroll
    for (int j = 0; j < 4; ++j) {
        const unsigned short hi = f2bf(vv[j]);
        hp[j] = hi;
        lp[j] = f2bf(vv[j] - bf2f(hi));
    }
    ((ushort4*)dh)[i] = h4;
    ((ushort4*)dl)[i] = l4;
}

// ---------------------------------------------------------------------------
// Split-bf16 MFMA GEMM: C[M, N=1024] = A[M,K=1024] @ B[N,K]^T
// acc = Ah*Bh + Al*Bh + Ah*Bl (fp32 MFMA accumulate).
// 128x128 tile, 4 waves (each 64x64). Fragment-major LDS filled by
// global_load_lds width=16: block g holds rows [16g,16g+16) x k[0,32)
// in exact MFMA lane order (lane = m + 16*kq, 16B per lane) -> conflict-free
// ds_read_b128 and zero staging VGPRs.
// MODE 0: store raw  MODE 1: store sigmoid(z)  MODE 2: store silu(z)*(1-Faux)
// ---------------------------------------------------------------------------
template<int MODE>
__global__ __launch_bounds__(256) void gemm_split(
    const unsigned short* __restrict__ Ah, const unsigned short* __restrict__ Al,
    const unsigned short* __restrict__ Bh, const unsigned short* __restrict__ Bl,
    const float* __restrict__ Faux, float* __restrict__ C)
{
    __shared__ __align__(16) unsigned short As_h[128 * 32];
    __shared__ __align__(16) unsigned short As_l[128 * 32];
    __shared__ __align__(16) unsigned short Bs_h[128 * 32];
    __shared__ __align__(16) unsigned short Bs_l[128 * 32];

    const int tid  = threadIdx.x;
    const int lane = tid & 63;
    const int wave = tid >> 6;
    const int wm   = (wave & 1) * 64;   // wave m-origin in tile
    const int wn   = (wave >> 1) * 64;  // wave n-origin in tile
    const int lm   = lane & 15;
    const int kq   = lane >> 4;         // k-quad 0..3
    const int m0   = blockIdx.y * 128;
    const int n0   = blockIdx.x * 128;

    // wave w fills one matrix (0:Ah 1:Al 2:Bh 3:Bl), all 8 row-groups.
    // per-lane source: row = base + g*16 + lm, col = k0 + kq*8
    const unsigned short* gsrc;
    unsigned short* ldst;
    {
        const size_t arow = (size_t)(m0 + lm) * Hh + kq * 8;
        const size_t brow = (size_t)(n0 + lm) * Hh + kq * 8;
        gsrc = (wave == 0) ? Ah + arow : (wave == 1) ? Al + arow
             : (wave == 2) ? Bh + brow : Bl + brow;
        ldst = (wave == 0) ? As_h : (wave == 1) ? As_l
             : (wave == 2) ? Bs_h : Bs_l;
    }

    f32x4 acc[4][4] = {};
    const int lo = lane * 8;   // shorts; lane's 16B slot within a block

    for (int k0 = 0; k0 < Hh; k0 += 32) {
        __syncthreads();  // previous iteration's LDS readers done
        #pragma unroll
        for (int g = 0; g < 8; ++g)
            gl2lds16(gsrc + (size_t)(g * 16) * Hh + k0, ldst + g * 512 + lo);
        __syncthreads();  // drains vmcnt (global_load_lds) + lgkm

        s16x8 ah[4], al[4], bh[4], bl[4];
        #pragma unroll
        for (int t = 0; t < 4; ++t) {
            const int ia = ((wm >> 4) + t) * 512 + lo;
            const int ib = ((wn >> 4) + t) * 512 + lo;
            ah[t] = *(const s16x8*)&As_h[ia];
            al[t] = *(const s16x8*)&As_l[ia];
            bh[t] = *(const s16x8*)&Bs_h[ib];
            bl[t] = *(const s16x8*)&Bs_l[ib];
        }
        #pragma unroll
        for (int mi = 0; mi < 4; ++mi)
            #pragma unroll
            for (int ni = 0; ni < 4; ++ni) {
                acc[mi][ni] = __builtin_amdgcn_mfma_f32_16x16x32_bf16(ah[mi], bh[ni], acc[mi][ni], 0, 0, 0);
                acc[mi][ni] = __builtin_amdgcn_mfma_f32_16x16x32_bf16(al[mi], bh[ni], acc[mi][ni], 0, 0, 0);
                acc[mi][ni] = __builtin_amdgcn_mfma_f32_16x16x32_bf16(ah[mi], bl[ni], acc[mi][ni], 0, 0, 0);
            }
    }

    // epilogue: D[row = kq*4 + r][col = lm] per 16x16 tile (verified mapping)
    #pragma unroll
    for (int mi = 0; mi < 4; ++mi)
        #pragma unroll
        for (int ni = 0; ni < 4; ++ni) {
            const int n = n0 + wn + ni * 16 + lm;
            #pragma unroll
            for (int r = 0; r < 4; ++r) {
                const int m = m0 + wm + mi * 16 + kq * 4 + r;
                const size_t idx = (size_t)m * Hh + n;
                const float z = acc[mi][ni][r];
                float v;
                if (MODE == 0)      v = z;
                else if (MODE == 1) v = sigf(z);
                else                v = z * sigf(z) * (1.0f - Faux[idx]);
                C[idx] = v;
            }
        }
}

// ---------------------------------------------------------------------------
// Recurrence pass 1: per (b,h,chunk) compute P = prod(f), L = local final h
// ---------------------------------------------------------------------------
__global__ __launch_bounds__(256) void scan1(
    const float* __restrict__ f, const float* __restrict__ ip,
    float2* __restrict__ csum)
{
    const int g  = blockIdx.x * 256 + threadIdx.x;  // 0..131071
    const int c  = g >> 12;                          // chunk 0..31
    const int bh = g & 4095;
    const size_t base = (size_t)(bh >> 10) * ((size_t)Ss * Hh) + (bh & 1023);
    const int s0 = c * CL;
    float P = 1.0f, L = 0.0f;
    for (int j = 0; j < CL; j += 4) {
        float fv[4], iv[4];
        #pragma unroll
        for (int q = 0; q < 4; ++q) {
            const size_t off = base + (size_t)(s0 + j + q) * Hh;
            fv[q] = f[off]; iv[q] = ip[off];
        }
        #pragma unroll
        for (int q = 0; q < 4; ++q) { L = fmaf(fv[q], L, iv[q]); P *= fv[q]; }
    }
    csum[(size_t)bh * NC + c] = make_float2(P, L);
}

// ---------------------------------------------------------------------------
// Recurrence pass 2: combine chunk prefixes, replay chunk, emit gh as bf16 hi/lo
// ---------------------------------------------------------------------------
__global__ __launch_bounds__(256) void scan2(
    const float* __restrict__ f, const float* __restrict__ ip,
    const float* __restrict__ gbuf, const float2* __restrict__ csum,
    unsigned short* __restrict__ ghh, unsigned short* __restrict__ ghl)
{
    const int g  = blockIdx.x * 256 + threadIdx.x;
    const int c  = g >> 12;
    const int bh = g & 4095;
    const size_t base = (size_t)(bh >> 10) * ((size_t)Ss * Hh) + (bh & 1023);
    float h = 0.0f;
    for (int cp = 0; cp < c; ++cp) {
        const float2 pl = csum[(size_t)bh * NC + cp];
        h = fmaf(pl.x, h, pl.y);
    }
    const int s0 = c * CL;
    for (int j = 0; j < CL; j += 4) {
        float fv[4], iv[4], gv[4];
        #pragma unroll
        for (int q = 0; q < 4; ++q) {
            const size_t off = base + (size_t)(s0 + j + q) * Hh;
            fv[q] = f[off]; iv[q] = ip[off]; gv[q] = gbuf[off];
        }
        #pragma unroll
        for (int q = 0; q < 4; ++q) {
            h = fmaf(fv[q], h, iv[q]);
            const float gh = gv[q] * h;
            const unsigned short hi = f2bf(gh);
            const size_t off = base + (size_t)(s0 + j + q) * Hh;
            ghh[off] = hi;
            ghl[off] = f2bf(gh - bf2f(hi));
        }
    }
}

// ===========================================================================
// Round-1 fp32 fallback (used only if ws_size is too small for the split path)
// ===========================================================================
__global__ __launch_bounds__(256) void proj_kernel(
    const float* __restrict__ x,  const float* __restrict__ Wi,
    const float* __restrict__ Wf, const float* __restrict__ Wg,
    float* __restrict__ f_out, float* __restrict__ inp_out, float* __restrict__ g_out)
{
    __shared__ __align__(16) float As [16][68];
    __shared__ __align__(16) float Bis[16][68];
    __shared__ __align__(16) float Bfs[16][68];
    __shared__ __align__(16) float Bgs[16][68];
    const int tid = threadIdx.x;
    const int tx = tid & 15, ty = tid >> 4;
    const int m0 = blockIdx.x * 64, n0 = blockIdx.y * 64;
    const int lr = tid >> 2, lk = (tid & 3) << 2;
    float acc_i[4][4] = {}, acc_f[4][4] = {}, acc_g[4][4] = {};
    const float* pA = x  + (size_t)(m0 + lr) * Hh + lk;
    const float* pI = Wi + (size_t)(n0 + lr) * Hh + lk;
    const float* pF = Wf + (size_t)(n0 + lr) * Hh + lk;
    const float* pG = Wg + (size_t)(n0 + lr) * Hh + lk;
    for (int k0 = 0; k0 < Hh; k0 += 16) {
        const float4 av = *(const float4*)(pA + k0);
        const float4 iv = *(const float4*)(pI + k0);
        const float4 fv = *(const float4*)(pF + k0);
        const float4 gv = *(const float4*)(pG + k0);
        __syncthreads();
        As [lk+0][lr] = av.x; As [lk+1][lr] = av.y; As [lk+2][lr] = av.z; As [lk+3][lr] = av.w;
        Bis[lk+0][lr] = iv.x; Bis[lk+1][lr] = iv.y; Bis[lk+2][lr] = iv.z; Bis[lk+3][lr] = iv.w;
        Bfs[lk+0][lr] = fv.x; Bfs[lk+1][lr] = fv.y; Bfs[lk+2][lr] = fv.z; Bfs[lk+3][lr] = fv.w;
        Bgs[lk+0][lr] = gv.x; Bgs[lk+1][lr] = gv.y; Bgs[lk+2][lr] = gv.z; Bgs[lk+3][lr] = gv.w;
        __syncthreads();
        #pragma unroll
        for (int kk = 0; kk < 16; ++kk) {
            const float4 a  = *(const float4*)&As [kk][ty << 2];
            const float4 bi = *(const float4*)&Bis[kk][tx << 2];
            const float4 bf = *(const float4*)&Bfs[kk][tx << 2];
            const float4 bg = *(const float4*)&Bgs[kk][tx << 2];
            const float aa[4]  = {a.x,a.y,a.z,a.w};
            const float bbi[4] = {bi.x,bi.y,bi.z,bi.w};
            const float bbf[4] = {bf.x,bf.y,bf.z,bf.w};
            const float bbg[4] = {bg.x,bg.y,bg.z,bg.w};
            #pragma unroll
            for (int i = 0; i < 4; ++i)
                #pragma unroll
                for (int j = 0; j < 4; ++j) {
                    acc_i[i][j] = fmaf(aa[i], bbi[j], acc_i[i][j]);
                    acc_f[i][j] = fmaf(aa[i], bbf[j], acc_f[i][j]);
                    acc_g[i][j] = fmaf(aa[i], bbg[j], acc_g[i][j]);
                }
        }
    }
    #pragma unroll
    for (int i = 0; i < 4; ++i) {
        const size_t row = (size_t)(m0 + (ty << 2) + i) * Hh + n0 + (tx << 2);
        float4 vf, vp, vg;
        float* qf = (float*)&vf; float* qp = (float*)&vp; float* qg = (float*)&vg;
        #pragma unroll
        for (int j = 0; j < 4; ++j) {
            const float ff = sigf(acc_f[i][j]);
            const float zi = acc_i[i][j];
            qf[j] = ff; qp[j] = zi * sigf(zi) * (1.0f - ff); qg[j] = acc_g[i][j];
        }
        *(float4*)(f_out + row) = vf;
        *(float4*)(inp_out + row) = vp;
        *(float4*)(g_out + row) = vg;
    }
}

__global__ __launch_bounds__(256) void recur_kernel(
    const float* f_buf, const float* __restrict__ inp_buf,
    const float* __restrict__ g_buf, float* gh_out)
{
    const int t = blockIdx.x * 256 + threadIdx.x;
    const int b = t >> 10, h = t & 1023;
    const size_t base = (size_t)b * Ss * Hh + h;
    float hh = 0.0f;
    for (int s0 = 0; s0 < Ss; s0 += 8) {
        float fr[8], ir[8], gr[8], o[8];
        #pragma unroll
        for (int j = 0; j < 8; ++j) {
            const size_t off = base + (size_t)(s0 + j) * Hh;
            fr[j] = f_buf[off]; ir[j] = inp_buf[off]; gr[j] = g_buf[off];
        }
        #pragma unroll
        for (int j = 0; j < 8; ++j) { hh = fmaf(fr[j], hh, ir[j]); o[j] = gr[j] * hh; }
        #pragma unroll
        for (int j = 0; j < 8; ++j) gh_out[base + (size_t)(s0 + j) * Hh] = o[j];
    }
}

__global__ __launch_bounds__(256) void out_kernel(
    const float* __restrict__ A, const float* __restrict__ Wo, float* __restrict__ out)
{
    __shared__ __align__(16) float As[16][68];
    __shared__ __align__(16) float Bs[16][68];
    const int tid = threadIdx.x;
    const int tx = tid & 15, ty = tid >> 4;
    const int m0 = blockIdx.x * 64, n0 = blockIdx.y * 64;
    const int lr = tid >> 2, lk = (tid & 3) << 2;
    float acc[4][4] = {};
    const float* pA = A  + (size_t)(m0 + lr) * Hh + lk;
    const float* pB = Wo + (size_t)(n0 + lr) * Hh + lk;
    for (int k0 = 0; k0 < Hh; k0 += 16) {
        const float4 av = *(const float4*)(pA + k0);
        const float4 bv = *(const float4*)(pB + k0);
        __syncthreads();
        As[lk+0][lr] = av.x; As[lk+1][lr] = av.y; As[lk+2][lr] = av.z; As[lk+3][lr] = av.w;
        Bs[lk+0][lr] = bv.x; Bs[lk+1][lr] = bv.y; Bs[lk+2][lr] = bv.z; Bs[lk+3][lr] = bv.w;
        __syncthreads();
        #pragma unroll
        for (int kk = 0; kk < 16; ++kk) {
            const float4 a = *(const float4*)&As[kk][ty << 2];
            const float4 b = *(const float4*)&Bs[kk][tx << 2];
            const float aa[4] = {a.x,a.y,a.z,a.w};
            const float bb[4] = {b.x,b.y,b.z,b.w};
            #pragma unroll
            for (int i = 0; i < 4; ++i)
                #pragma unroll
                for (int j = 0; j < 4; ++j)
                    acc[i][j] = fmaf(aa[i], bb[j], acc[i][j]);
        }
    }
    #pragma unroll
    for (int i = 0; i < 4; ++i) {
        const size_t row = (size_t)(m0 + (ty << 2) + i) * Hh + n0 + (tx << 2);
        float4 v;
        ((float*)&v)[0]=acc[i][0]; ((float*)&v)[1]=acc[i][1];
        ((float*)&v)[2]=acc[i][2]; ((float*)&v)[3]=acc[i][3];
        *(float4*)(out + row) = v;
    }
}

extern "C" void kernel_launch(void* const* d_in, const int* in_sizes, int n_in,
                              void* d_out, int out_size, void* d_ws, size_t ws_size,
                              hipStream_t stream) {
    const float* x  = (const float*)d_in[0];
    const float* Wi = (const float*)d_in[1];
    const float* Wf = (const float*)d_in[2];
    const float* Wg = (const float*)d_in[3];
    const float* Wo = (const float*)d_in[4];
    float* out = (float*)d_out;

    const size_t MH = (size_t)Mm * Hh;      // 8388608
    const size_t HH = (size_t)Hh * Hh;      // 1048576

    size_t need = MH*2*2 + HH*4*2*2 + MH*4*2 + MH*2*2 + (size_t)4096*NC*8;

    if (ws_size >= need) {
        char* p = (char*)d_ws;
        unsigned short* xh = (unsigned short*)p;            p += MH*2;
        unsigned short* xl = (unsigned short*)p;            p += MH*2;
        unsigned short* Wh = (unsigned short*)p;            p += HH*4*2;
        unsigned short* Wl = (unsigned short*)p;            p += HH*4*2;
        float* f_buf   = (float*)p;                         p += MH*4;
        float* inp_buf = (float*)p;                         p += MH*4;
        unsigned short* ghh = (unsigned short*)p;           p += MH*2;
        unsigned short* ghl = (unsigned short*)p;           p += MH*2;
        float2* csum = (float2*)p;

        unsigned short* Wih = Wh;          unsigned short* Wil = Wl;
        unsigned short* Wfh = Wh + HH;     unsigned short* Wfl = Wl + HH;
        unsigned short* Wgh = Wh + 2*HH;   unsigned short* Wgl = Wl + 2*HH;
        unsigned short* Woh = Wh + 3*HH;   unsigned short* Wol = Wl + 3*HH;

        conv_split<<<(int)(MH/4/256), 256, 0, stream>>>(x,  xh,  xl,  (int)(MH/4));
        conv_split<<<(int)(HH/4/256), 256, 0, stream>>>(Wi, Wih, Wil, (int)(HH/4));
        conv_split<<<(int)(HH/4/256), 256, 0, stream>>>(Wf, Wfh, Wfl, (int)(HH/4));
        conv_split<<<(int)(HH/4/256), 256, 0, stream>>>(Wg, Wgh, Wgl, (int)(HH/4));
        conv_split<<<(int)(HH/4/256), 256, 0, stream>>>(Wo, Woh, Wol, (int)(HH/4));

        dim3 gg(Hh/128, Mm/128);  // (8, 64)
        gemm_split<1><<<gg, 256, 0, stream>>>(xh, xl, Wfh, Wfl, nullptr, f_buf);
        gemm_split<2><<<gg, 256, 0, stream>>>(xh, xl, Wih, Wil, f_buf, inp_buf);
        gemm_split<0><<<gg, 256, 0, stream>>>(xh, xl, Wgh, Wgl, nullptr, out);
        scan1<<<512, 256, 0, stream>>>(f_buf, inp_buf, csum);
        scan2<<<512, 256, 0, stream>>>(f_buf, inp_buf, out, csum, ghh, ghl);
        gemm_split<0><<<gg, 256, 0, stream>>>(ghh, ghl, Woh, Wol, nullptr, out);
    } else {
        float* f_buf   = (float*)d_ws;
        float* inp_buf = f_buf + MH;
        dim3 grid(Mm / 64, Hh / 64);
        proj_kernel<<<grid, 256, 0, stream>>>(x, Wi, Wf, Wg, f_buf, inp_buf, out);
        recur_kernel<<<16, 256, 0, stream>>>(f_buf, inp_buf, out, f_buf);
        out_kernel<<<grid, 256, 0, stream>>>(f_buf, Wo, out);
    }
}

// Round 4
// 406.504 us; speedup vs baseline: 2.5715x; 1.0221x over previous
//
#include <hip/hip_runtime.h>

#define Bb 4
#define Ss 2048
#define Hh 1024
#define Mm (Bb * Ss)   // 8192 rows
#define NC 32          // recurrence chunks
#define CL 64          // chunk length (NC*CL == Ss)

typedef short  s16x8 __attribute__((ext_vector_type(8)));
typedef float  f32x4 __attribute__((ext_vector_type(4)));

__device__ __forceinline__ float sigf(float z) { return 1.0f / (1.0f + __expf(-z)); }

// bf16 round-to-nearest-even helpers (bit-level, no API dependence)
__device__ __forceinline__ unsigned short f2bf(float x) {
    unsigned int u = __float_as_uint(x);
    u += 0x7FFFu + ((u >> 16) & 1u);
    return (unsigned short)(u >> 16);
}
__device__ __forceinline__ float bf2f(unsigned short h) {
    return __uint_as_float(((unsigned int)h) << 16);
}

// async global->LDS, 16B per lane (lane0-consistent pointers)
__device__ __forceinline__ void gl2lds16(const unsigned short* g, unsigned short* l) {
    __builtin_amdgcn_global_load_lds(
        (const __attribute__((address_space(1))) void*)g,
        (__attribute__((address_space(3))) void*)l,
        16, 0, 0);
}

// ---------------------------------------------------------------------------
// Split fp32 -> (bf16 hi, bf16 lo), 4 elems/thread
// ---------------------------------------------------------------------------
__global__ __launch_bounds__(256) void conv_split(
    const float* __restrict__ src, unsigned short* __restrict__ dh,
    unsigned short* __restrict__ dl, int n4)
{
    const int i = blockIdx.x * 256 + threadIdx.x;
    if (i >= n4) return;
    const float4 v = ((const float4*)src)[i];
    ushort4 h4, l4;
    const float vv[4] = {v.x, v.y, v.z, v.w};
    unsigned short* hp = (unsigned short*)&h4;
    unsigned short* lp = (unsigned short*)&l4;
    #pragma unroll
    for (int j = 0; j < 4; ++j) {
        const unsigned short hi = f2bf(vv[j]);
        hp[j] = hi;
        lp[j] = f2bf(vv[j] - bf2f(hi));
    }
    ((ushort4*)dh)[i] = h4;
    ((ushort4*)dl)[i] = l4;
}

// all 4 weights in one dispatch; dst row-block = blockIdx.y * H
// layout: rows 0-1023 Wi, 1024-2047 Wf, 2048-3071 Wg, 3072-4095 Wo
__global__ __launch_bounds__(256) void conv_w4(
    const float* __restrict__ W0, const float* __restrict__ W1,
    const float* __restrict__ W2, const float* __restrict__ W3,
    unsigned short* __restrict__ dh, unsigned short* __restrict__ dl)
{
    const int which = blockIdx.y;
    const float* src = (which == 0) ? W0 : (which == 1) ? W1 : (which == 2) ? W2 : W3;
    const int i = blockIdx.x * 256 + threadIdx.x;          // 0 .. HH/4-1
    const size_t o = (size_t)which * ((size_t)Hh * Hh / 4) + i;
    const float4 v = ((const float4*)src)[i];
    ushort4 h4, l4;
    const float vv[4] = {v.x, v.y, v.z, v.w};
    unsigned short* hp = (unsigned short*)&h4;
    unsigned short* lp = (unsigned short*)&l4;
    #pragma unroll
    for (int j = 0; j < 4; ++j) {
        const unsigned short hi = f2bf(vv[j]);
        hp[j] = hi;
        lp[j] = f2bf(vv[j] - bf2f(hi));
    }
    ((ushort4*)dh)[o] = h4;
    ((ushort4*)dl)[o] = l4;
}

// ---------------------------------------------------------------------------
// Split-bf16 MFMA GEMM: C[M, N] = A[M,K=1024] @ B[N,K]^T, raw store.
// acc = Ah*Bh + Al*Bh + Ah*Bl (fp32 MFMA accumulate).
// 128x128 tile, 4 waves (each 64x64). Fragment-major LDS via global_load_lds
// width=16 (zero staging VGPRs, conflict-free ds_read_b128).
// Columns n < nsplit -> C0 (ld0); n >= nsplit -> C1 at col n-nsplit (ld1).
// ---------------------------------------------------------------------------
__global__ __launch_bounds__(256) void gemm_split(
    const unsigned short* __restrict__ Ah, const unsigned short* __restrict__ Al,
    const unsigned short* __restrict__ Bh, const unsigned short* __restrict__ Bl,
    float* __restrict__ C0, int ld0, float* __restrict__ C1, int ld1, int nsplit)
{
    __shared__ __align__(16) unsigned short As_h[128 * 32];
    __shared__ __align__(16) unsigned short As_l[128 * 32];
    __shared__ __align__(16) unsigned short Bs_h[128 * 32];
    __shared__ __align__(16) unsigned short Bs_l[128 * 32];

    const int tid  = threadIdx.x;
    const int lane = tid & 63;
    const int wave = tid >> 6;
    const int wm   = (wave & 1) * 64;
    const int wn   = (wave >> 1) * 64;
    const int lm   = lane & 15;
    const int kq   = lane >> 4;
    const int m0   = blockIdx.y * 128;
    const int n0   = blockIdx.x * 128;

    // wave w fills one matrix (0:Ah 1:Al 2:Bh 3:Bl), 8 row-groups each
    const unsigned short* gsrc;
    unsigned short* ldst;
    {
        const size_t arow = (size_t)(m0 + lm) * Hh + kq * 8;
        const size_t brow = (size_t)(n0 + lm) * Hh + kq * 8;
        gsrc = (wave == 0) ? Ah + arow : (wave == 1) ? Al + arow
             : (wave == 2) ? Bh + brow : Bl + brow;
        ldst = (wave == 0) ? As_h : (wave == 1) ? As_l
             : (wave == 2) ? Bs_h : Bs_l;
    }

    f32x4 acc[4][4] = {};
    const int lo = lane * 8;   // lane's 16B slot within a fragment block

    for (int k0 = 0; k0 < Hh; k0 += 32) {
        __syncthreads();
        #pragma unroll
        for (int g = 0; g < 8; ++g)
            gl2lds16(gsrc + (size_t)(g * 16) * Hh + k0, ldst + g * 512 + lo);
        __syncthreads();

        s16x8 ah[4], al[4], bh[4], bl[4];
        #pragma unroll
        for (int t = 0; t < 4; ++t) {
            const int ia = ((wm >> 4) + t) * 512 + lo;
            const int ib = ((wn >> 4) + t) * 512 + lo;
            ah[t] = *(const s16x8*)&As_h[ia];
            al[t] = *(const s16x8*)&As_l[ia];
            bh[t] = *(const s16x8*)&Bs_h[ib];
            bl[t] = *(const s16x8*)&Bs_l[ib];
        }
        #pragma unroll
        for (int mi = 0; mi < 4; ++mi)
            #pragma unroll
            for (int ni = 0; ni < 4; ++ni) {
                acc[mi][ni] = __builtin_amdgcn_mfma_f32_16x16x32_bf16(ah[mi], bh[ni], acc[mi][ni], 0, 0, 0);
                acc[mi][ni] = __builtin_amdgcn_mfma_f32_16x16x32_bf16(al[mi], bh[ni], acc[mi][ni], 0, 0, 0);
                acc[mi][ni] = __builtin_amdgcn_mfma_f32_16x16x32_bf16(ah[mi], bl[ni], acc[mi][ni], 0, 0, 0);
            }
    }

    // epilogue: D[row = kq*4 + r][col = lm] per 16x16 tile
    #pragma unroll
    for (int mi = 0; mi < 4; ++mi)
        #pragma unroll
        for (int ni = 0; ni < 4; ++ni) {
            const int n = n0 + wn + ni * 16 + lm;
            const bool sec = (n >= nsplit);
            float* Cp  = sec ? C1 : C0;
            const int ld = sec ? ld1 : ld0;
            const int nn = sec ? n - nsplit : n;
            #pragma unroll
            for (int r = 0; r < 4; ++r) {
                const int m = m0 + wm + mi * 16 + kq * 4 + r;
                Cp[(size_t)m * ld + nn] = acc[mi][ni][r];
            }
        }
}

// ---------------------------------------------------------------------------
// Recurrence pass 1: per (b,h,chunk) compute P = prod(f), L = local final h
// reads raw z_i,z_f from zif[M,2048] (cols 0-1023 z_i, 1024-2047 z_f)
// ---------------------------------------------------------------------------
__global__ __launch_bounds__(256) void scan1(
    const float* __restrict__ zif, float2* __restrict__ csum)
{
    const int g  = blockIdx.x * 256 + threadIdx.x;  // 0..131071
    const int c  = g >> 12;                          // chunk 0..31
    const int bh = g & 4095;
    const int b  = bh >> 10, h = bh & 1023;
    const size_t base = (size_t)b * Ss * 2048 + h;
    const int s0 = c * CL;
    float P = 1.0f, L = 0.0f;
    for (int j = 0; j < CL; j += 4) {
        float zi[4], zf[4];
        #pragma unroll
        for (int q = 0; q < 4; ++q) {
            const size_t off = base + (size_t)(s0 + j + q) * 2048;
            zi[q] = zif[off]; zf[q] = zif[off + 1024];
        }
        #pragma unroll
        for (int q = 0; q < 4; ++q) {
            const float f  = sigf(zf[q]);
            const float ip = zi[q] * sigf(zi[q]) * (1.0f - f);
            L = fmaf(f, L, ip); P *= f;
        }
    }
    csum[(size_t)bh * NC + c] = make_float2(P, L);
}

// ---------------------------------------------------------------------------
// Recurrence pass 2: combine chunk prefixes, replay chunk, emit gh as bf16 hi/lo
// ---------------------------------------------------------------------------
__global__ __launch_bounds__(256) void scan2(
    const float* __restrict__ zif, const float* __restrict__ zg,
    const float2* __restrict__ csum,
    unsigned short* __restrict__ ghh, unsigned short* __restrict__ ghl)
{
    const int g  = blockIdx.x * 256 + threadIdx.x;
    const int c  = g >> 12;
    const int bh = g & 4095;
    const int b  = bh >> 10, h = bh & 1023;
    const size_t base  = (size_t)b * Ss * 2048 + h;   // zif
    const size_t baseg = (size_t)b * Ss * 1024 + h;   // zg / gh
    float hh = 0.0f;
    for (int cp = 0; cp < c; ++cp) {
        const float2 pl = csum[(size_t)bh * NC + cp];
        hh = fmaf(pl.x, hh, pl.y);
    }
    const int s0 = c * CL;
    for (int j = 0; j < CL; j += 4) {
        float zi[4], zf[4], gv[4];
        #pragma unroll
        for (int q = 0; q < 4; ++q) {
            const size_t off = base + (size_t)(s0 + j + q) * 2048;
            zi[q] = zif[off]; zf[q] = zif[off + 1024];
            gv[q] = zg[baseg + (size_t)(s0 + j + q) * 1024];
        }
        #pragma unroll
        for (int q = 0; q < 4; ++q) {
            const float f  = sigf(zf[q]);
            const float ip = zi[q] * sigf(zi[q]) * (1.0f - f);
            hh = fmaf(f, hh, ip);
            const float gh = gv[q] * hh;
            const unsigned short hi = f2bf(gh);
            const size_t off = baseg + (size_t)(s0 + j + q) * 1024;
            ghh[off] = hi;
            ghl[off] = f2bf(gh - bf2f(hi));
        }
    }
}

// ===========================================================================
// Round-1 fp32 fallback (only if ws_size is too small for the split path)
// ===========================================================================
__global__ __launch_bounds__(256) void proj_kernel(
    const float* __restrict__ x,  const float* __restrict__ Wi,
    const float* __restrict__ Wf, const float* __restrict__ Wg,
    float* __restrict__ f_out, float* __restrict__ inp_out, float* __restrict__ g_out)
{
    __shared__ __align__(16) float As [16][68];
    __shared__ __align__(16) float Bis[16][68];
    __shared__ __align__(16) float Bfs[16][68];
    __shared__ __align__(16) float Bgs[16][68];
    const int tid = threadIdx.x;
    const int tx = tid & 15, ty = tid >> 4;
    const int m0 = blockIdx.x * 64, n0 = blockIdx.y * 64;
    const int lr = tid >> 2, lk = (tid & 3) << 2;
    float acc_i[4][4] = {}, acc_f[4][4] = {}, acc_g[4][4] = {};
    const float* pA = x  + (size_t)(m0 + lr) * Hh + lk;
    const float* pI = Wi + (size_t)(n0 + lr) * Hh + lk;
    const float* pF = Wf + (size_t)(n0 + lr) * Hh + lk;
    const float* pG = Wg + (size_t)(n0 + lr) * Hh + lk;
    for (int k0 = 0; k0 < Hh; k0 += 16) {
        const float4 av = *(const float4*)(pA + k0);
        const float4 iv = *(const float4*)(pI + k0);
        const float4 fv = *(const float4*)(pF + k0);
        const float4 gv = *(const float4*)(pG + k0);
        __syncthreads();
        As [lk+0][lr] = av.x; As [lk+1][lr] = av.y; As [lk+2][lr] = av.z; As [lk+3][lr] = av.w;
        Bis[lk+0][lr] = iv.x; Bis[lk+1][lr] = iv.y; Bis[lk+2][lr] = iv.z; Bis[lk+3][lr] = iv.w;
        Bfs[lk+0][lr] = fv.x; Bfs[lk+1][lr] = fv.y; Bfs[lk+2][lr] = fv.z; Bfs[lk+3][lr] = fv.w;
        Bgs[lk+0][lr] = gv.x; Bgs[lk+1][lr] = gv.y; Bgs[lk+2][lr] = gv.z; Bgs[lk+3][lr] = gv.w;
        __syncthreads();
        #pragma unroll
        for (int kk = 0; kk < 16; ++kk) {
            const float4 a  = *(const float4*)&As [kk][ty << 2];
            const float4 bi = *(const float4*)&Bis[kk][tx << 2];
            const float4 bf = *(const float4*)&Bfs[kk][tx << 2];
            const float4 bg = *(const float4*)&Bgs[kk][tx << 2];
            const float aa[4]  = {a.x,a.y,a.z,a.w};
            const float bbi[4] = {bi.x,bi.y,bi.z,bi.w};
            const float bbf[4] = {bf.x,bf.y,bf.z,bf.w};
            const float bbg[4] = {bg.x,bg.y,bg.z,bg.w};
            #pragma unroll
            for (int i = 0; i < 4; ++i)
                #pragma unroll
                for (int j = 0; j < 4; ++j) {
                    acc_i[i][j] = fmaf(aa[i], bbi[j], acc_i[i][j]);
                    acc_f[i][j] = fmaf(aa[i], bbf[j], acc_f[i][j]);
                    acc_g[i][j] = fmaf(aa[i], bbg[j], acc_g[i][j]);
                }
        }
    }
    #pragma unroll
    for (int i = 0; i < 4; ++i) {
        const size_t row = (size_t)(m0 + (ty << 2) + i) * Hh + n0 + (tx << 2);
        float4 vf, vp, vg;
        float* qf = (float*)&vf; float* qp = (float*)&vp; float* qg = (float*)&vg;
        #pragma unroll
        for (int j = 0; j < 4; ++j) {
            const float ff = sigf(acc_f[i][j]);
            const float zi = acc_i[i][j];
            qf[j] = ff; qp[j] = zi * sigf(zi) * (1.0f - ff); qg[j] = acc_g[i][j];
        }
        *(float4*)(f_out + row) = vf;
        *(float4*)(inp_out + row) = vp;
        *(float4*)(g_out + row) = vg;
    }
}

__global__ __launch_bounds__(256) void recur_kernel(
    const float* f_buf, const float* __restrict__ inp_buf,
    const float* __restrict__ g_buf, float* gh_out)
{
    const int t = blockIdx.x * 256 + threadIdx.x;
    const int b = t >> 10, h = t & 1023;
    const size_t base = (size_t)b * Ss * Hh + h;
    float hh = 0.0f;
    for (int s0 = 0; s0 < Ss; s0 += 8) {
        float fr[8], ir[8], gr[8], o[8];
        #pragma unroll
        for (int j = 0; j < 8; ++j) {
            const size_t off = base + (size_t)(s0 + j) * Hh;
            fr[j] = f_buf[off]; ir[j] = inp_buf[off]; gr[j] = g_buf[off];
        }
        #pragma unroll
        for (int j = 0; j < 8; ++j) { hh = fmaf(fr[j], hh, ir[j]); o[j] = gr[j] * hh; }
        #pragma unroll
        for (int j = 0; j < 8; ++j) gh_out[base + (size_t)(s0 + j) * Hh] = o[j];
    }
}

__global__ __launch_bounds__(256) void out_kernel(
    const float* __restrict__ A, const float* __restrict__ Wo, float* __restrict__ out)
{
    __shared__ __align__(16) float As[16][68];
    __shared__ __align__(16) float Bs[16][68];
    const int tid = threadIdx.x;
    const int tx = tid & 15, ty = tid >> 4;
    const int m0 = blockIdx.x * 64, n0 = blockIdx.y * 64;
    const int lr = tid >> 2, lk = (tid & 3) << 2;
    float acc[4][4] = {};
    const float* pA = A  + (size_t)(m0 + lr) * Hh + lk;
    const float* pB = Wo + (size_t)(n0 + lr) * Hh + lk;
    for (int k0 = 0; k0 < Hh; k0 += 16) {
        const float4 av = *(const float4*)(pA + k0);
        const float4 bv = *(const float4*)(pB + k0);
        __syncthreads();
        As[lk+0][lr] = av.x; As[lk+1][lr] = av.y; As[lk+2][lr] = av.z; As[lk+3][lr] = av.w;
        Bs[lk+0][lr] = bv.x; Bs[lk+1][lr] = bv.y; Bs[lk+2][lr] = bv.z; Bs[lk+3][lr] = bv.w;
        __syncthreads();
        #pragma unroll
        for (int kk = 0; kk < 16; ++kk) {
            const float4 a = *(const float4*)&As[kk][ty << 2];
            const float4 b = *(const float4*)&Bs[kk][tx << 2];
            const float aa[4] = {a.x,a.y,a.z,a.w};
            const float bb[4] = {b.x,b.y,b.z,b.w};
            #pragma unroll
            for (int i = 0; i < 4; ++i)
                #pragma unroll
                for (int j = 0; j < 4; ++j)
                    acc[i][j] = fmaf(aa[i], bb[j], acc[i][j]);
        }
    }
    #pragma unroll
    for (int i = 0; i < 4; ++i) {
        const size_t row = (size_t)(m0 + (ty << 2) + i) * Hh + n0 + (tx << 2);
        float4 v;
        ((float*)&v)[0]=acc[i][0]; ((float*)&v)[1]=acc[i][1];
        ((float*)&v)[2]=acc[i][2]; ((float*)&v)[3]=acc[i][3];
        *(float4*)(out + row) = v;
    }
}

extern "C" void kernel_launch(void* const* d_in, const int* in_sizes, int n_in,
                              void* d_out, int out_size, void* d_ws, size_t ws_size,
                              hipStream_t stream) {
    const float* x  = (const float*)d_in[0];
    const float* Wi = (const float*)d_in[1];
    const float* Wf = (const float*)d_in[2];
    const float* Wg = (const float*)d_in[3];
    const float* Wo = (const float*)d_in[4];
    float* out = (float*)d_out;

    const size_t MH = (size_t)Mm * Hh;      // 8388608
    const size_t HH = (size_t)Hh * Hh;      // 1048576

    // ws layout (split path), 152 MB total:
    // xh[MH], xl[MH], Wallh[4HH], Walll[4HH] (rows: Wi,Wf,Wg,Wo),
    // zif[M*2048]f32, ghh[MH], ghl[MH], csum[4096*NC]float2
    size_t need = MH*2*2 + HH*4*2*2 + MH*2*4 + MH*2*2 + (size_t)4096*NC*8;

    if (ws_size >= need) {
        char* p = (char*)d_ws;
        unsigned short* xh    = (unsigned short*)p;  p += MH*2;
        unsigned short* xl    = (unsigned short*)p;  p += MH*2;
        unsigned short* Wallh = (unsigned short*)p;  p += HH*4*2;
        unsigned short* Walll = (unsigned short*)p;  p += HH*4*2;
        float* zif            = (float*)p;           p += MH*2*4;
        unsigned short* ghh   = (unsigned short*)p;  p += MH*2;
        unsigned short* ghl   = (unsigned short*)p;  p += MH*2;
        float2* csum          = (float2*)p;

        conv_split<<<(int)(MH/4/256), 256, 0, stream>>>(x, xh, xl, (int)(MH/4));
        conv_w4<<<dim3((unsigned)(HH/4/256), 4), 256, 0, stream>>>(Wi, Wf, Wg, Wo, Wallh, Walll);

        // fused projections: N=3072 (Wi|Wf|Wg); cols <2048 -> zif, >=2048 (z_g) -> d_out
        gemm_split<<<dim3(24, 64), 256, 0, stream>>>(
            xh, xl, Wallh, Walll, zif, 2048, out, 1024, 2048);

        scan1<<<512, 256, 0, stream>>>(zif, csum);
        scan2<<<512, 256, 0, stream>>>(zif, out, csum, ghh, ghl);

        // out = gh @ Wo^T  (Wo rows live at offset 3*HH in the concat)
        gemm_split<<<dim3(8, 64), 256, 0, stream>>>(
            ghh, ghl, Wallh + 3*HH, Walll + 3*HH, out, 1024, out, 1024, 1 << 30);
    } else {
        float* f_buf   = (float*)d_ws;
        float* inp_buf = f_buf + MH;
        dim3 grid(Mm / 64, Hh / 64);
        proj_kernel<<<grid, 256, 0, stream>>>(x, Wi, Wf, Wg, f_buf, inp_buf, out);
        recur_kernel<<<16, 256, 0, stream>>>(f_buf, inp_buf, out, f_buf);
        out_kernel<<<grid, 256, 0, stream>>>(f_buf, Wo, out);
    }
}

// Round 8
// 405.655 us; speedup vs baseline: 2.5769x; 1.0021x over previous
//
#include <hip/hip_runtime.h>

#define Bb 4
#define Ss 2048
#define Hh 1024
#define Mm (Bb * Ss)   // 8192 rows
#define NC 32          // recurrence chunks
#define CL 64          // chunk length (NC*CL == Ss)

typedef short  s16x8 __attribute__((ext_vector_type(8)));
typedef float  f32x4 __attribute__((ext_vector_type(4)));

__device__ __forceinline__ float sigf(float z) { return 1.0f / (1.0f + __expf(-z)); }

// bf16 round-to-nearest-even helpers (bit-level, no API dependence)
__device__ __forceinline__ unsigned short f2bf(float x) {
    unsigned int u = __float_as_uint(x);
    u += 0x7FFFu + ((u >> 16) & 1u);
    return (unsigned short)(u >> 16);
}
__device__ __forceinline__ float bf2f(unsigned short h) {
    return __uint_as_float(((unsigned int)h) << 16);
}

// async global->LDS, 16B per lane (lane0-consistent pointers)
__device__ __forceinline__ void gl2lds16(const unsigned short* g, unsigned short* l) {
    __builtin_amdgcn_global_load_lds(
        (const __attribute__((address_space(1))) void*)g,
        (__attribute__((address_space(3))) void*)l,
        16, 0, 0);
}

// ---------------------------------------------------------------------------
// Split fp32 -> (bf16 hi, bf16 lo), 4 elems/thread
// ---------------------------------------------------------------------------
__global__ __launch_bounds__(256) void conv_split(
    const float* __restrict__ src, unsigned short* __restrict__ dh,
    unsigned short* __restrict__ dl, int n4)
{
    const int i = blockIdx.x * 256 + threadIdx.x;
    if (i >= n4) return;
    const float4 v = ((const float4*)src)[i];
    ushort4 h4, l4;
    const float vv[4] = {v.x, v.y, v.z, v.w};
    unsigned short* hp = (unsigned short*)&h4;
    unsigned short* lp = (unsigned short*)&l4;
    #pragma unroll
    for (int j = 0; j < 4; ++j) {
        const unsigned short hi = f2bf(vv[j]);
        hp[j] = hi;
        lp[j] = f2bf(vv[j] - bf2f(hi));
    }
    ((ushort4*)dh)[i] = h4;
    ((ushort4*)dl)[i] = l4;
}

// all 4 weights in one dispatch; dst row-block = blockIdx.y * H
// layout: rows 0-1023 Wi, 1024-2047 Wf, 2048-3071 Wg, 3072-4095 Wo
__global__ __launch_bounds__(256) void conv_w4(
    const float* __restrict__ W0, const float* __restrict__ W1,
    const float* __restrict__ W2, const float* __restrict__ W3,
    unsigned short* __restrict__ dh, unsigned short* __restrict__ dl)
{
    const int which = blockIdx.y;
    const float* src = (which == 0) ? W0 : (which == 1) ? W1 : (which == 2) ? W2 : W3;
    const int i = blockIdx.x * 256 + threadIdx.x;          // 0 .. HH/4-1
    const size_t o = (size_t)which * ((size_t)Hh * Hh / 4) + i;
    const float4 v = ((const float4*)src)[i];
    ushort4 h4, l4;
    const float vv[4] = {v.x, v.y, v.z, v.w};
    unsigned short* hp = (unsigned short*)&h4;
    unsigned short* lp = (unsigned short*)&l4;
    #pragma unroll
    for (int j = 0; j < 4; ++j) {
        const unsigned short hi = f2bf(vv[j]);
        hp[j] = hi;
        lp[j] = f2bf(vv[j] - bf2f(hi));
    }
    ((ushort4*)dh)[o] = h4;
    ((ushort4*)dl)[o] = l4;
}

// ---------------------------------------------------------------------------
// Split-bf16 MFMA GEMM: C[M, N] = A[M,K=1024] @ B[N,K]^T, raw store.
// acc = Ah*Bh + Al*Bh + Ah*Bl (fp32 MFMA accumulate).
// 128x128 tile, 4 waves (each 64x64 = 4x4 tiles of 16x16x32). Fragment-major
// LDS via global_load_lds width=16 (zero staging VGPRs, conflict-free
// ds_read_b128).
// Columns n < nsplit -> C0 (ld0); n >= nsplit -> C1 at col n-nsplit (ld1).
// ---------------------------------------------------------------------------
__global__ __launch_bounds__(256) void gemm_split(
    const unsigned short* __restrict__ Ah, const unsigned short* __restrict__ Al,
    const unsigned short* __restrict__ Bh, const unsigned short* __restrict__ Bl,
    float* __restrict__ C0, int ld0, float* __restrict__ C1, int ld1, int nsplit)
{
    __shared__ __align__(16) unsigned short As_h[128 * 32];
    __shared__ __align__(16) unsigned short As_l[128 * 32];
    __shared__ __align__(16) unsigned short Bs_h[128 * 32];
    __shared__ __align__(16) unsigned short Bs_l[128 * 32];

    const int tid  = threadIdx.x;
    const int lane = tid & 63;
    const int wave = tid >> 6;
    const int wm   = (wave & 1) * 64;
    const int wn   = (wave >> 1) * 64;
    const int lm   = lane & 15;
    const int kq   = lane >> 4;
    const int m0   = blockIdx.y * 128;
    const int n0   = blockIdx.x * 128;

    // wave w fills one matrix (0:Ah 1:Al 2:Bh 3:Bl), 8 row-groups each
    const unsigned short* gsrc;
    unsigned short* ldst;
    {
        const size_t arow = (size_t)(m0 + lm) * Hh + kq * 8;
        const size_t brow = (size_t)(n0 + lm) * Hh + kq * 8;
        gsrc = (wave == 0) ? Ah + arow : (wave == 1) ? Al + arow
             : (wave == 2) ? Bh + brow : Bl + brow;
        ldst = (wave == 0) ? As_h : (wave == 1) ? As_l
             : (wave == 2) ? Bs_h : Bs_l;
    }

    f32x4 acc[4][4] = {};
    const int lo = lane * 8;   // lane's 16B slot within a fragment block

    for (int k0 = 0; k0 < Hh; k0 += 32) {
        __syncthreads();
        #pragma unroll
        for (int g = 0; g < 8; ++g)
            gl2lds16(gsrc + (size_t)(g * 16) * Hh + k0, ldst + g * 512 + lo);
        __syncthreads();

        s16x8 ah[4], al[4], bh[4], bl[4];
        #pragma unroll
        for (int t = 0; t < 4; ++t) {
            const int ia = ((wm >> 4) + t) * 512 + lo;
            const int ib = ((wn >> 4) + t) * 512 + lo;
            ah[t] = *(const s16x8*)&As_h[ia];
            al[t] = *(const s16x8*)&As_l[ia];
            bh[t] = *(const s16x8*)&Bs_h[ib];
            bl[t] = *(const s16x8*)&Bs_l[ib];
        }
        #pragma unroll
        for (int mi = 0; mi < 4; ++mi)
            #pragma unroll
            for (int ni = 0; ni < 4; ++ni) {
                acc[mi][ni] = __builtin_amdgcn_mfma_f32_16x16x32_bf16(ah[mi], bh[ni], acc[mi][ni], 0, 0, 0);
                acc[mi][ni] = __builtin_amdgcn_mfma_f32_16x16x32_bf16(al[mi], bh[ni], acc[mi][ni], 0, 0, 0);
                acc[mi][ni] = __builtin_amdgcn_mfma_f32_16x16x32_bf16(ah[mi], bl[ni], acc[mi][ni], 0, 0, 0);
            }
    }

    // epilogue: D[row = kq*4 + r][col = lm] per 16x16 tile
    #pragma unroll
    for (int mi = 0; mi < 4; ++mi)
        #pragma unroll
        for (int ni = 0; ni < 4; ++ni) {
            const int n = n0 + wn + ni * 16 + lm;
            const bool sec = (n >= nsplit);
            float* Cp  = sec ? C1 : C0;
            const int ld = sec ? ld1 : ld0;
            const int nn = sec ? n - nsplit : n;
            #pragma unroll
            for (int r = 0; r < 4; ++r) {
                const int m = m0 + wm + mi * 16 + kq * 4 + r;
                Cp[(size_t)m * ld + nn] = acc[mi][ni][r];
            }
        }
}

// ---------------------------------------------------------------------------
// Recurrence pass 1: per (b,h,chunk) compute P = prod(f), L = local final h
// reads raw z_i,z_f from zif[M,2048] (cols 0-1023 z_i, 1024-2047 z_f)
// ---------------------------------------------------------------------------
__global__ __launch_bounds__(256) void scan1(
    const float* __restrict__ zif, float2* __restrict__ csum)
{
    const int g  = blockIdx.x * 256 + threadIdx.x;  // 0..131071
    const int c  = g >> 12;                          // chunk 0..31
    const int bh = g & 4095;
    const int b  = bh >> 10, h = bh & 1023;
    const size_t base = (size_t)b * Ss * 2048 + h;
    const int s0 = c * CL;
    float P = 1.0f, L = 0.0f;
    for (int j = 0; j < CL; j += 4) {
        float zi[4], zf[4];
        #pragma unroll
        for (int q = 0; q < 4; ++q) {
            const size_t off = base + (size_t)(s0 + j + q) * 2048;
            zi[q] = zif[off]; zf[q] = zif[off + 1024];
        }
        #pragma unroll
        for (int q = 0; q < 4; ++q) {
            const float f  = sigf(zf[q]);
            const float ip = zi[q] * sigf(zi[q]) * (1.0f - f);
            L = fmaf(f, L, ip); P *= f;
        }
    }
    csum[(size_t)bh * NC + c] = make_float2(P, L);
}

// ---------------------------------------------------------------------------
// Recurrence pass 2: combine chunk prefixes, replay chunk, emit gh as bf16 hi/lo
// ---------------------------------------------------------------------------
__global__ __launch_bounds__(256) void scan2(
    const float* __restrict__ zif, const float* __restrict__ zg,
    const float2* __restrict__ csum,
    unsigned short* __restrict__ ghh, unsigned short* __restrict__ ghl)
{
    const int g  = blockIdx.x * 256 + threadIdx.x;
    const int c  = g >> 12;
    const int bh = g & 4095;
    const int b  = bh >> 10, h = bh & 1023;
    const size_t base  = (size_t)b * Ss * 2048 + h;   // zif
    const size_t baseg = (size_t)b * Ss * 1024 + h;   // zg / gh
    float hh = 0.0f;
    for (int cp = 0; cp < c; ++cp) {
        const float2 pl = csum[(size_t)bh * NC + cp];
        hh = fmaf(pl.x, hh, pl.y);
    }
    const int s0 = c * CL;
    for (int j = 0; j < CL; j += 4) {
        float zi[4], zf[4], gv[4];
        #pragma unroll
        for (int q = 0; q < 4; ++q) {
            const size_t off = base + (size_t)(s0 + j + q) * 2048;
            zi[q] = zif[off]; zf[q] = zif[off + 1024];
            gv[q] = zg[baseg + (size_t)(s0 + j + q) * 1024];
        }
        #pragma unroll
        for (int q = 0; q < 4; ++q) {
            const float f  = sigf(zf[q]);
            const float ip = zi[q] * sigf(zi[q]) * (1.0f - f);
            hh = fmaf(f, hh, ip);
            const float gh = gv[q] * hh;
            const unsigned short hi = f2bf(gh);
            const size_t off = baseg + (size_t)(s0 + j + q) * 1024;
            ghh[off] = hi;
            ghl[off] = f2bf(gh - bf2f(hi));
        }
    }
}

// ===========================================================================
// Round-1 fp32 fallback (only if ws_size is too small for the split path)
// ===========================================================================
__global__ __launch_bounds__(256) void proj_kernel(
    const float* __restrict__ x,  const float* __restrict__ Wi,
    const float* __restrict__ Wf, const float* __restrict__ Wg,
    float* __restrict__ f_out, float* __restrict__ inp_out, float* __restrict__ g_out)
{
    __shared__ __align__(16) float As [16][68];
    __shared__ __align__(16) float Bis[16][68];
    __shared__ __align__(16) float Bfs[16][68];
    __shared__ __align__(16) float Bgs[16][68];
    const int tid = threadIdx.x;
    const int tx = tid & 15, ty = tid >> 4;
    const int m0 = blockIdx.x * 64, n0 = blockIdx.y * 64;
    const int lr = tid >> 2, lk = (tid & 3) << 2;
    float acc_i[4][4] = {}, acc_f[4][4] = {}, acc_g[4][4] = {};
    const float* pA = x  + (size_t)(m0 + lr) * Hh + lk;
    const float* pI = Wi + (size_t)(n0 + lr) * Hh + lk;
    const float* pF = Wf + (size_t)(n0 + lr) * Hh + lk;
    const float* pG = Wg + (size_t)(n0 + lr) * Hh + lk;
    for (int k0 = 0; k0 < Hh; k0 += 16) {
        const float4 av = *(const float4*)(pA + k0);
        const float4 iv = *(const float4*)(pI + k0);
        const float4 fv = *(const float4*)(pF + k0);
        const float4 gv = *(const float4*)(pG + k0);
        __syncthreads();
        As [lk+0][lr] = av.x; As [lk+1][lr] = av.y; As [lk+2][lr] = av.z; As [lk+3][lr] = av.w;
        Bis[lk+0][lr] = iv.x; Bis[lk+1][lr] = iv.y; Bis[lk+2][lr] = iv.z; Bis[lk+3][lr] = iv.w;
        Bfs[lk+0][lr] = fv.x; Bfs[lk+1][lr] = fv.y; Bfs[lk+2][lr] = fv.z; Bfs[lk+3][lr] = fv.w;
        Bgs[lk+0][lr] = gv.x; Bgs[lk+1][lr] = gv.y; Bgs[lk+2][lr] = gv.z; Bgs[lk+3][lr] = gv.w;
        __syncthreads();
        #pragma unroll
        for (int kk = 0; kk < 16; ++kk) {
            const float4 a  = *(const float4*)&As [kk][ty << 2];
            const float4 bi = *(const float4*)&Bis[kk][tx << 2];
            const float4 bf = *(const float4*)&Bfs[kk][tx << 2];
            const float4 bg = *(const float4*)&Bgs[kk][tx << 2];
            const float aa[4]  = {a.x,a.y,a.z,a.w};
            const float bbi[4] = {bi.x,bi.y,bi.z,bi.w};
            const float bbf[4] = {bf.x,bf.y,bf.z,bf.w};
            const float bbg[4] = {bg.x,bg.y,bg.z,bg.w};
            #pragma unroll
            for (int i = 0; i < 4; ++i)
                #pragma unroll
                for (int j = 0; j < 4; ++j) {
                    acc_i[i][j] = fmaf(aa[i], bbi[j], acc_i[i][j]);
                    acc_f[i][j] = fmaf(aa[i], bbf[j], acc_f[i][j]);
                    acc_g[i][j] = fmaf(aa[i], bbg[j], acc_g[i][j]);
                }
        }
    }
    #pragma unroll
    for (int i = 0; i < 4; ++i) {
        const size_t row = (size_t)(m0 + (ty << 2) + i) * Hh + n0 + (tx << 2);
        float4 vf, vp, vg;
        float* qf = (float*)&vf; float* qp = (float*)&vp; float* qg = (float*)&vg;
        #pragma unroll
        for (int j = 0; j < 4; ++j) {
            const float ff = sigf(acc_f[i][j]);
            const float zi = acc_i[i][j];
            qf[j] = ff; qp[j] = zi * sigf(zi) * (1.0f - ff); qg[j] = acc_g[i][j];
        }
        *(float4*)(f_out + row) = vf;
        *(float4*)(inp_out + row) = vp;
        *(float4*)(g_out + row) = vg;
    }
}

__global__ __launch_bounds__(256) void recur_kernel(
    const float* f_buf, const float* __restrict__ inp_buf,
    const float* __restrict__ g_buf, float* gh_out)
{
    const int t = blockIdx.x * 256 + threadIdx.x;
    const int b = t >> 10, h = t & 1023;
    const size_t base = (size_t)b * Ss * Hh + h;
    float hh = 0.0f;
    for (int s0 = 0; s0 < Ss; s0 += 8) {
        float fr[8], ir[8], gr[8], o[8];
        #pragma unroll
        for (int j = 0; j < 8; ++j) {
            const size_t off = base + (size_t)(s0 + j) * Hh;
            fr[j] = f_buf[off]; ir[j] = inp_buf[off]; gr[j] = g_buf[off];
        }
        #pragma unroll
        for (int j = 0; j < 8; ++j) { hh = fmaf(fr[j], hh, ir[j]); o[j] = gr[j] * hh; }
        #pragma unroll
        for (int j = 0; j < 8; ++j) gh_out[base + (size_t)(s0 + j) * Hh] = o[j];
    }
}

__global__ __launch_bounds__(256) void out_kernel(
    const float* __restrict__ A, const float* __restrict__ Wo, float* __restrict__ out)
{
    __shared__ __align__(16) float As[16][68];
    __shared__ __align__(16) float Bs[16][68];
    const int tid = threadIdx.x;
    const int tx = tid & 15, ty = tid >> 4;
    const int m0 = blockIdx.x * 64, n0 = blockIdx.y * 64;
    const int lr = tid >> 2, lk = (tid & 3) << 2;
    float acc[4][4] = {};
    const float* pA = A  + (size_t)(m0 + lr) * Hh + lk;
    const float* pB = Wo + (size_t)(n0 + lr) * Hh + lk;
    for (int k0 = 0; k0 < Hh; k0 += 16) {
        const float4 av = *(const float4*)(pA + k0);
        const float4 bv = *(const float4*)(pB + k0);
        __syncthreads();
        As[lk+0][lr] = av.x; As[lk+1][lr] = av.y; As[lk+2][lr] = av.z; As[lk+3][lr] = av.w;
        Bs[lk+0][lr] = bv.x; Bs[lk+1][lr] = bv.y; Bs[lk+2][lr] = bv.z; Bs[lk+3][lr] = bv.w;
        __syncthreads();
        #pragma unroll
        for (int kk = 0; kk < 16; ++kk) {
            const float4 a = *(const float4*)&As[kk][ty << 2];
            const float4 b = *(const float4*)&Bs[kk][tx << 2];
            const float aa[4] = {a.x,a.y,a.z,a.w};
            const float bb[4] = {b.x,b.y,b.z,b.w};
            #pragma unroll
            for (int i = 0; i < 4; ++i)
                #pragma unroll
                for (int j = 0; j < 4; ++j)
                    acc[i][j] = fmaf(aa[i], bb[j], acc[i][j]);
        }
    }
    #pragma unroll
    for (int i = 0; i < 4; ++i) {
        const size_t row = (size_t)(m0 + (ty << 2) + i) * Hh + n0 + (tx << 2);
        float4 v;
        ((float*)&v)[0]=acc[i][0]; ((float*)&v)[1]=acc[i][1];
        ((float*)&v)[2]=acc[i][2]; ((float*)&v)[3]=acc[i][3];
        *(float4*)(out + row) = v;
    }
}

extern "C" void kernel_launch(void* const* d_in, const int* in_sizes, int n_in,
                              void* d_out, int out_size, void* d_ws, size_t ws_size,
                              hipStream_t stream) {
    const float* x  = (const float*)d_in[0];
    const float* Wi = (const float*)d_in[1];
    const float* Wf = (const float*)d_in[2];
    const float* Wg = (const float*)d_in[3];
    const float* Wo = (const float*)d_in[4];
    float* out = (float*)d_out;

    const size_t MH = (size_t)Mm * Hh;      // 8388608
    const size_t HH = (size_t)Hh * Hh;      // 1048576

    // ws layout (split path), ~152 MB:
    // xh[MH], xl[MH], Wallh[4HH], Walll[4HH] (rows: Wi,Wf,Wg,Wo),
    // zif[M*2048]f32, ghh[MH], ghl[MH], csum[4096*NC]float2
    size_t need = MH*2*2 + HH*4*2*2 + MH*2*4 + MH*2*2 + (size_t)4096*NC*8;

    if (ws_size >= need) {
        char* p = (char*)d_ws;
        unsigned short* xh    = (unsigned short*)p;  p += MH*2;
        unsigned short* xl    = (unsigned short*)p;  p += MH*2;
        unsigned short* Wallh = (unsigned short*)p;  p += HH*4*2;
        unsigned short* Walll = (unsigned short*)p;  p += HH*4*2;
        float* zif            = (float*)p;           p += MH*2*4;
        unsigned short* ghh   = (unsigned short*)p;  p += MH*2;
        unsigned short* ghl   = (unsigned short*)p;  p += MH*2;
        float2* csum          = (float2*)p;

        conv_split<<<(int)(MH/4/256), 256, 0, stream>>>(x, xh, xl, (int)(MH/4));
        conv_w4<<<dim3((unsigned)(HH/4/256/1), 4), 256, 0, stream>>>(Wi, Wf, Wg, Wo, Wallh, Walll);

        // fused projections: N=3072 (Wi|Wf|Wg); cols <2048 -> zif, >=2048 (z_g) -> d_out
        gemm_split<<<dim3(24, 64), 256, 0, stream>>>(
            xh, xl, Wallh, Walll, zif, 2048, out, 1024, 2048);

        scan1<<<512, 256, 0, stream>>>(zif, csum);
        scan2<<<512, 256, 0, stream>>>(zif, out, csum, ghh, ghl);

        // out = gh @ Wo^T  (Wo rows live at offset 3*HH in the concat)
        gemm_split<<<dim3(8, 64), 256, 0, stream>>>(
            ghh, ghl, Wallh + 3*HH, Walll + 3*HH, out, 1024, out, 1024, 1 << 30);
    } else {
        float* f_buf   = (float*)d_ws;
        float* inp_buf = f_buf + MH;
        dim3 grid(Mm / 64, Hh / 64);
        proj_kernel<<<grid, 256, 0, stream>>>(x, Wi, Wf, Wg, f_buf, inp_buf, out);
        recur_kernel<<<16, 256, 0, stream>>>(f_buf, inp_buf, out, f_buf);
        out_kernel<<<grid, 256, 0, stream>>>(f_buf, Wo, out);
    }
}